// Round 11
// baseline (114.048 us; speedup 1.0000x reference)
//
#include <hip/hip_runtime.h>
#include <math.h>

#define T_STEPS 200
#define BB 512
#define DD 32
#define LMBD 1.0f
#define NCH 4          // t-chunks per b
#define CHT 50         // t per chunk

// ws layout (floats)
#define WS_MINV 0                  // sigma^{-T} [i][k], 1024
#define WS_A    1024               // A = sigma sigma^T, 1024
#define WS_W    2048               // weight[512]
#define WS_PART 2560               // per-b partials [512]
#define WS_CT   3072               // chunk c-totals [512][4][32]
#define WS_Y    (3072 + 65536)     // chunk Y [512][4][32]
#define WS_M    (3072 + 131072)    // chunk <A,M> scalars [512][4]

// LDS-only barrier: all cross-thread traffic in the stream loop goes through
// LDS, and global loads feed only the issuing thread's registers — so we need
// lgkmcnt(0) + s_barrier, NOT the vmcnt(0) drain __syncthreads() emits.
// This keeps the cross-iteration nb-tile prefetch actually in flight (T4).
#define BAR_LDS() do {                                            \
    asm volatile("s_waitcnt lgkmcnt(0)" ::: "memory");            \
    __builtin_amdgcn_s_barrier();                                 \
    asm volatile("" ::: "memory");                                \
} while (0)

// ---------------------------------------------------------------------------
// Kernel 1: prep. weight = exp(lpd+lps+ltw); A = sigma sigma^T;
// sigma^{-T} via single-wave register Gauss-Jordan (no pivoting; sigma ~ I).
// ---------------------------------------------------------------------------
__global__ __launch_bounds__(512) void prep_kernel(
    const float* __restrict__ sigma,
    const float* __restrict__ lpd, const float* __restrict__ lps,
    const float* __restrict__ ltw,
    float* __restrict__ ws)
{
    __shared__ float sg[32][33];
    const int tid = threadIdx.x;

    ws[WS_W + tid] = expf(lpd[tid] + lps[tid] + ltw[tid]);

    for (int idx = tid; idx < 1024; idx += 512)
        sg[idx >> 5][idx & 31] = sigma[idx];
    __syncthreads();

    for (int idx = tid; idx < 1024; idx += 512) {
        int i = idx >> 5, j = idx & 31;
        float s = 0.0f;
        #pragma unroll
        for (int k = 0; k < 32; ++k) s += sg[i][k] * sg[j][k];
        ws[WS_A + idx] = s;
    }

    if (tid < 64) {
        const int l = tid;
        float col[32];
        #pragma unroll
        for (int r = 0; r < 32; ++r) {
            float v = sg[r][l & 31];
            col[r] = (l < 32) ? v : ((r == (l - 32)) ? 1.0f : 0.0f);
        }
        #pragma unroll
        for (int k = 0; k < 32; ++k) {
            float pinv = 1.0f / __shfl(col[k], k);
            col[k] *= pinv;
            #pragma unroll
            for (int r = 0; r < 32; ++r) {
                if (r == k) continue;
                float f = __shfl(col[r], k);
                col[r] -= f * col[k];
            }
        }
        if (l >= 32) {   // lane 32+c holds sigma^{-1} col c; Minv[i][k]=inv[k][i]
            #pragma unroll
            for (int r = 0; r < 32; ++r)
                ws[WS_MINV + (l - 32) * 32 + r] = col[r];
        }
    }
}

// ---------------------------------------------------------------------------
// Kernel 2 (stream): R10 champion; ONLY change is 2-deep nb-tile register
// prefetch (hold t, t+1, t+2; +4 VGPR) so the tile load has ~1.7 iterations
// of slack vs ~900cy HBM latency instead of ~0.7.
// Block = (chunk h, b). Streams nabla_b once; per t:
//   v = Minv * (-sqrt(dt)*n - dt*ctl)       (octet dot + shfl reduce)
//   y(t) = P(t-1) + V(t);  c_t = dt*f + nb.v;  P += c_t
//   Y += y;  M += y y^T   (thread (r,q) holds M[r][4q..4q+3])
// ---------------------------------------------------------------------------
__global__ __launch_bounds__(256) void stream_kernel(
    const float* __restrict__ ts,
    const float* __restrict__ noises,
    const float* __restrict__ controls,
    const float* __restrict__ nabla_f,
    const float* __restrict__ nabla_V,
    const float* __restrict__ nabla_b,
    float* __restrict__ ws)
{
    __shared__ float ts_l[52];
    __shared__ __align__(16) float buf[2][4][32];   // [parity][n,ctl,f,V][i]
    __shared__ __align__(16) float vls[32];
    __shared__ __align__(16) float yls[32];
    __shared__ float red[256];

    const int h   = blockIdx.x;        // 0..3
    const int b   = blockIdx.y;        // 0..511
    const int tid = threadIdx.x;
    const int r   = tid >> 3;          // 0..31 (row / i)
    const int q   = tid & 7;           // 0..7  (4-col group)
    const int w   = tid >> 6;          // wave 0..3
    const int lane = tid & 63;

    const int t0 = h * CHT, t1 = t0 + CHT;

    // per-wave small-array pointer (wave-uniform)
    const float* sp_w = (w == 0) ? noises : (w == 1) ? controls
                       : (w == 2) ? nabla_f : nabla_V;

    // stage ts[t0 .. t0+50]
    if (tid < 51) ts_l[tid] = ts[t0 + tid];
    // stage smalls for t0
    if (lane < 32) buf[0][w][lane] = sp_w[((size_t)t0 * BB + b) * DD + lane];

    // Minv fragment: row r, cols 4q..4q+3 of sigma^{-T}
    float4 Minv4 = *(const float4*)(ws + WS_MINV + r * 32 + 4 * q);

    // 2-deep tile prefetch: t0 and t0+1
    const float4* nb4 = (const float4*)nabla_b;
    float4 nbCur = nb4[(size_t)(t0 * BB + b) * 256 + tid];
    const int t0b = (t0 + 1 < t1) ? t0 + 1 : t1 - 1;
    float4 nbN1  = nb4[(size_t)(t0b * BB + b) * 256 + tid];

    float P = 0.0f, Yacc = 0.0f;
    float a0 = 0.f, a1 = 0.f, a2 = 0.f, a3 = 0.f;
    __syncthreads();

    for (int t = t0; t < t1; ++t) {
        const int p = t & 1;           // t0 even -> starts at 0
        // --- issue prefetches: nb tile for t+2 (2-deep), smalls for t+1
        const int tn2 = (t + 2 < t1) ? t + 2 : t1 - 1;
        float4 nbN2 = nb4[(size_t)(tn2 * BB + b) * 256 + tid];
        const int tn = (t + 1 < t1) ? t + 1 : t1 - 1;
        float smallNext = 0.0f;
        if (lane < 32) smallNext = sp_w[((size_t)tn * BB + b) * DD + lane];

        const float dt  = ts_l[t - t0 + 1] - ts_l[t - t0];
        const float sdt = sqrtf(LMBD * dt);

        // --- v phase: v_r = sum_k Minv[r][k] * w_k
        {
            float4 n4 = *(const float4*)&buf[p][0][4 * q];
            float4 c4 = *(const float4*)&buf[p][1][4 * q];
            float wx = -sdt * n4.x - dt * c4.x;
            float wy = -sdt * n4.y - dt * c4.y;
            float wz = -sdt * n4.z - dt * c4.z;
            float ww = -sdt * n4.w - dt * c4.w;
            float pv = Minv4.x * wx + Minv4.y * wy + Minv4.z * wz + Minv4.w * ww;
            pv += __shfl_xor(pv, 1);
            pv += __shfl_xor(pv, 2);
            pv += __shfl_xor(pv, 4);
            if (q == 0) vls[r] = pv;
        }
        BAR_LDS();         // B1: vls visible (LDS-only fence)

        // --- y, c, P phase  (+ staging of next smalls, parity-disjoint)
        float yr;
        {
            float Vt = buf[p][3][r];
            yr = P + Vt;                       // uses P(t-1)
            if (q == 0) yls[r] = yr;
            float4 v4 = *(const float4*)&vls[4 * q];
            float pc = nbCur.x * v4.x + nbCur.y * v4.y
                     + nbCur.z * v4.z + nbCur.w * v4.w;
            pc += __shfl_xor(pc, 1);
            pc += __shfl_xor(pc, 2);
            pc += __shfl_xor(pc, 4);
            float fr = buf[p][2][r];
            P += dt * fr + pc;                 // P(t)
            Yacc += yr;
        }
        if (lane < 32) buf[p ^ 1][w][lane] = smallNext;
        BAR_LDS();         // B2: yls visible; buf[p^1] fenced for next iter

        // --- M accumulate: M[r][4q+k] += y_r * y_{4q+k}
        {
            float4 y4 = *(const float4*)&yls[4 * q];
            a0 += yr * y4.x; a1 += yr * y4.y; a2 += yr * y4.z; a3 += yr * y4.w;
        }
        // rotate 2-deep pipeline
        nbCur = nbN1; nbN1 = nbN2;
    }

    __syncthreads();   // protect tail yls write vs last M-phase reads

    // tail: t = 200 belongs to last chunk: y(200) = P + V(200)
    if (h == NCH - 1) {
        float Vt = nabla_V[((size_t)T_STEPS * BB + b) * DD + r];
        float yr = P + Vt;
        if (q == 0) yls[r] = yr;
        Yacc += yr;
        __syncthreads();
        float4 y4 = *(const float4*)&yls[4 * q];
        a0 += yr * y4.x; a1 += yr * y4.y; a2 += yr * y4.z; a3 += yr * y4.w;
        __syncthreads();
    }

    // chunk epilogue: m = <A, M>, write CT / Y / m
    {
        float4 A4 = *(const float4*)(ws + WS_A + r * 32 + 4 * q);
        float mp = a0 * A4.x + a1 * A4.y + a2 * A4.z + a3 * A4.w;
        red[tid] = mp;
        __syncthreads();
        for (int st = 128; st > 0; st >>= 1) {
            if (tid < st) red[tid] += red[tid + st];
            __syncthreads();
        }
        if (q == 0) {
            ws[WS_CT + (b * NCH + h) * 32 + r] = P;
            ws[WS_Y  + (b * NCH + h) * 32 + r] = Yacc;
        }
        if (tid == 0) ws[WS_M + b * NCH + h] = red[0];
    }
}

// ---------------------------------------------------------------------------
// Kernel 3 (combine): per b, resolve cross-chunk prefix algebra:
//   S = g + sum_h CT_h ; C_h = prefix ; S'_h = S - C_h
//   loss_b = w_b * sum_h [ n_h S'^T A S' - 2 S'^T A Y_h + m_h ]
// ---------------------------------------------------------------------------
__global__ __launch_bounds__(256) void combine_kernel(
    const float* __restrict__ nabla_g,
    float* __restrict__ ws)
{
    __shared__ float ct[NCH][32], Yl[NCH][32];
    __shared__ float Sv[32], Cp[32];
    __shared__ __align__(16) float sp[32];
    __shared__ float red[32];

    const int b   = blockIdx.x;
    const int tid = threadIdx.x;
    const int r   = tid >> 3;
    const int q   = tid & 7;

    if (tid < NCH * 32) {
        int hh = tid >> 5, i = tid & 31;
        ct[hh][i] = ws[WS_CT + (b * NCH + hh) * 32 + i];
        Yl[hh][i] = ws[WS_Y  + (b * NCH + hh) * 32 + i];
    }
    if (tid < 32) Cp[tid] = 0.0f;
    __syncthreads();
    if (tid < 32) {
        float s = nabla_g[b * 32 + tid];
        #pragma unroll
        for (int hh = 0; hh < NCH; ++hh) s += ct[hh][tid];
        Sv[tid] = s;
    }

    float acc = 0.0f;
    float4 A4 = *(const float4*)(ws + WS_A + r * 32 + 4 * q);
    for (int hh = 0; hh < NCH; ++hh) {
        __syncthreads();
        if (tid < 32) sp[tid] = Sv[tid] - Cp[tid];
        __syncthreads();
        float4 s4 = *(const float4*)&sp[4 * q];
        float as = A4.x * s4.x + A4.y * s4.y + A4.z * s4.z + A4.w * s4.w;
        as += __shfl_xor(as, 1);
        as += __shfl_xor(as, 2);
        as += __shfl_xor(as, 4);
        float nh = (hh == NCH - 1) ? (float)(CHT + 1) : (float)CHT;
        if (q == 0) acc += as * (nh * sp[r] - 2.0f * Yl[hh][r]);
        if (tid < 32) Cp[tid] += ct[hh][tid];
    }
    __syncthreads();
    if (q == 0) red[r] = acc;
    __syncthreads();
    if (tid == 0) {
        float s = 0.0f;
        #pragma unroll
        for (int i = 0; i < 32; ++i) s += red[i];
        #pragma unroll
        for (int hh = 0; hh < NCH; ++hh) s += ws[WS_M + b * NCH + hh];
        ws[WS_PART + b] = ws[WS_W + b] * s;
    }
}

// ---------------------------------------------------------------------------
// Kernel 4: deterministic final reduction
// ---------------------------------------------------------------------------
__global__ __launch_bounds__(512) void reduce_kernel(
    const float* __restrict__ ws, float* __restrict__ out)
{
    __shared__ float r[512];
    const int tid = threadIdx.x;
    r[tid] = ws[WS_PART + tid];
    __syncthreads();
    for (int st = 256; st > 0; st >>= 1) {
        if (tid < st) r[tid] += r[tid + st];
        __syncthreads();
    }
    if (tid == 0) out[0] = r[0] * (1.0f / (201.0f * 512.0f));
}

extern "C" void kernel_launch(void* const* d_in, const int* in_sizes, int n_in,
                              void* d_out, int out_size, void* d_ws, size_t ws_size,
                              hipStream_t stream) {
    (void)in_sizes; (void)n_in; (void)out_size; (void)ws_size;
    const float* ts       = (const float*)d_in[0];
    const float* noises   = (const float*)d_in[2];
    const float* controls = (const float*)d_in[3];
    const float* nabla_V  = (const float*)d_in[4];
    const float* nabla_f  = (const float*)d_in[5];
    const float* nabla_b  = (const float*)d_in[6];
    const float* nabla_g  = (const float*)d_in[7];
    const float* sigma    = (const float*)d_in[8];
    const float* lpd      = (const float*)d_in[9];
    const float* lps      = (const float*)d_in[10];
    const float* ltw      = (const float*)d_in[11];
    float* ws  = (float*)d_ws;
    float* out = (float*)d_out;

    prep_kernel<<<1, 512, 0, stream>>>(sigma, lpd, lps, ltw, ws);
    stream_kernel<<<dim3(NCH, BB), 256, 0, stream>>>(ts, noises, controls,
                                                     nabla_f, nabla_V, nabla_b, ws);
    combine_kernel<<<BB, 256, 0, stream>>>(nabla_g, ws);
    reduce_kernel<<<1, 512, 0, stream>>>(ws, out);
}

// Round 12
// 107.421 us; speedup vs baseline: 1.0617x; 1.0617x over previous
//
#include <hip/hip_runtime.h>
#include <math.h>

#define T_STEPS 200
#define BB 512
#define DD 32
#define LMBD 1.0f
#define NCH 4          // t-chunks per b
#define CHT 50         // t per chunk

// ws layout (floats)
#define WS_MINV 0                  // sigma^{-T} [i][k], 1024
#define WS_A    1024               // A = sigma sigma^T, 1024
#define WS_W    2048               // weight[512]
#define WS_PART 2560               // per-b partials [512]
#define WS_CT   3072               // chunk c-totals [512][4][32]
#define WS_Y    (3072 + 65536)     // chunk Y [512][4][32]
#define WS_M    (3072 + 131072)    // chunk <A,M> scalars [512][4]

// LDS-only barrier: all cross-thread traffic in the stream loop goes through
// LDS, and global loads feed only the issuing thread's registers — so we need
// lgkmcnt(0) + s_barrier, NOT the vmcnt(0) drain __syncthreads() emits.
// This keeps the cross-iteration nb-tile prefetch actually in flight (T4).
// "memory" clobbers pin LDS op ordering around the barrier (rule 18 guard).
#define BAR_LDS() do {                                            \
    asm volatile("s_waitcnt lgkmcnt(0)" ::: "memory");            \
    __builtin_amdgcn_s_barrier();                                 \
    asm volatile("" ::: "memory");                                \
} while (0)

// ---------------------------------------------------------------------------
// Kernel 1: prep. weight = exp(lpd+lps+ltw); A = sigma sigma^T;
// sigma^{-T} via single-wave register Gauss-Jordan (no pivoting; sigma ~ I).
// ---------------------------------------------------------------------------
__global__ __launch_bounds__(512) void prep_kernel(
    const float* __restrict__ sigma,
    const float* __restrict__ lpd, const float* __restrict__ lps,
    const float* __restrict__ ltw,
    float* __restrict__ ws)
{
    __shared__ float sg[32][33];
    const int tid = threadIdx.x;

    ws[WS_W + tid] = expf(lpd[tid] + lps[tid] + ltw[tid]);

    for (int idx = tid; idx < 1024; idx += 512)
        sg[idx >> 5][idx & 31] = sigma[idx];
    __syncthreads();

    for (int idx = tid; idx < 1024; idx += 512) {
        int i = idx >> 5, j = idx & 31;
        float s = 0.0f;
        #pragma unroll
        for (int k = 0; k < 32; ++k) s += sg[i][k] * sg[j][k];
        ws[WS_A + idx] = s;
    }

    if (tid < 64) {
        const int l = tid;
        float col[32];
        #pragma unroll
        for (int r = 0; r < 32; ++r) {
            float v = sg[r][l & 31];
            col[r] = (l < 32) ? v : ((r == (l - 32)) ? 1.0f : 0.0f);
        }
        #pragma unroll
        for (int k = 0; k < 32; ++k) {
            float pinv = 1.0f / __shfl(col[k], k);
            col[k] *= pinv;
            #pragma unroll
            for (int r = 0; r < 32; ++r) {
                if (r == k) continue;
                float f = __shfl(col[r], k);
                col[r] -= f * col[k];
            }
        }
        if (l >= 32) {   // lane 32+c holds sigma^{-1} col c; Minv[i][k]=inv[k][i]
            #pragma unroll
            for (int r = 0; r < 32; ++r)
                ws[WS_MINV + (l - 32) * 32 + r] = col[r];
        }
    }
}

// ---------------------------------------------------------------------------
// Kernel 2 (stream): measured champion (R10). Block = (chunk h, b).
// Streams nabla_b once; per t:
//   v = Minv * (-sqrt(dt)*n - dt*ctl)       (octet dot + shfl reduce)
//   y(t) = P(t-1) + V(t);  c_t = dt*f + nb.v;  P += c_t
//   Y += y;  M += y y^T   (thread (r,q) holds M[r][4q..4q+3])
// 1-deep register prefetch of the next nb tile; lgkm-only in-loop barriers.
// ---------------------------------------------------------------------------
__global__ __launch_bounds__(256) void stream_kernel(
    const float* __restrict__ ts,
    const float* __restrict__ noises,
    const float* __restrict__ controls,
    const float* __restrict__ nabla_f,
    const float* __restrict__ nabla_V,
    const float* __restrict__ nabla_b,
    float* __restrict__ ws)
{
    __shared__ float ts_l[52];
    __shared__ __align__(16) float buf[2][4][32];   // [parity][n,ctl,f,V][i]
    __shared__ __align__(16) float vls[32];
    __shared__ __align__(16) float yls[32];
    __shared__ float red[256];

    const int h   = blockIdx.x;        // 0..3
    const int b   = blockIdx.y;        // 0..511
    const int tid = threadIdx.x;
    const int r   = tid >> 3;          // 0..31 (row / i)
    const int q   = tid & 7;           // 0..7  (4-col group)
    const int w   = tid >> 6;          // wave 0..3
    const int lane = tid & 63;

    const int t0 = h * CHT, t1 = t0 + CHT;

    // per-wave small-array pointer (wave-uniform)
    const float* sp_w = (w == 0) ? noises : (w == 1) ? controls
                       : (w == 2) ? nabla_f : nabla_V;

    // stage ts[t0 .. t0+50]
    if (tid < 51) ts_l[tid] = ts[t0 + tid];
    // stage smalls for t0
    if (lane < 32) buf[0][w][lane] = sp_w[((size_t)t0 * BB + b) * DD + lane];

    // Minv fragment: row r, cols 4q..4q+3 of sigma^{-T}
    float4 Minv4 = *(const float4*)(ws + WS_MINV + r * 32 + 4 * q);
    // first nb tile (4KB, coalesced: lane reads float4 at tid)
    float4 nbCur = ((const float4*)nabla_b + (size_t)(t0 * BB + b) * 256)[tid];

    float P = 0.0f, Yacc = 0.0f;
    float a0 = 0.f, a1 = 0.f, a2 = 0.f, a3 = 0.f;
    __syncthreads();

    for (int t = t0; t < t1; ++t) {
        const int p = t & 1;           // t0 even -> starts at 0
        // --- issue prefetches for t+1 (clamped inside chunk); with
        // lgkm-only barriers these stay in flight across B1/B2.
        const int tn = (t + 1 < t1) ? t + 1 : t1 - 1;
        float4 nbNext = ((const float4*)nabla_b + (size_t)(tn * BB + b) * 256)[tid];
        float smallNext = 0.0f;
        if (lane < 32) smallNext = sp_w[((size_t)tn * BB + b) * DD + lane];

        const float dt  = ts_l[t - t0 + 1] - ts_l[t - t0];
        const float sdt = sqrtf(LMBD * dt);

        // --- v phase: v_r = sum_k Minv[r][k] * w_k
        {
            float4 n4 = *(const float4*)&buf[p][0][4 * q];
            float4 c4 = *(const float4*)&buf[p][1][4 * q];
            float wx = -sdt * n4.x - dt * c4.x;
            float wy = -sdt * n4.y - dt * c4.y;
            float wz = -sdt * n4.z - dt * c4.z;
            float ww = -sdt * n4.w - dt * c4.w;
            float pv = Minv4.x * wx + Minv4.y * wy + Minv4.z * wz + Minv4.w * ww;
            pv += __shfl_xor(pv, 1);
            pv += __shfl_xor(pv, 2);
            pv += __shfl_xor(pv, 4);
            if (q == 0) vls[r] = pv;
        }
        BAR_LDS();         // B1: vls visible (LDS-only fence)

        // --- y, c, P phase  (+ staging of next smalls, parity-disjoint)
        float yr;
        {
            float Vt = buf[p][3][r];
            yr = P + Vt;                       // uses P(t-1)
            if (q == 0) yls[r] = yr;
            float4 v4 = *(const float4*)&vls[4 * q];
            float pc = nbCur.x * v4.x + nbCur.y * v4.y
                     + nbCur.z * v4.z + nbCur.w * v4.w;
            pc += __shfl_xor(pc, 1);
            pc += __shfl_xor(pc, 2);
            pc += __shfl_xor(pc, 4);
            float fr = buf[p][2][r];
            P += dt * fr + pc;                 // P(t)
            Yacc += yr;
        }
        if (lane < 32) buf[p ^ 1][w][lane] = smallNext;
        BAR_LDS();         // B2: yls visible; buf[p^1] fenced for next iter

        // --- M accumulate: M[r][4q+k] += y_r * y_{4q+k}
        {
            float4 y4 = *(const float4*)&yls[4 * q];
            a0 += yr * y4.x; a1 += yr * y4.y; a2 += yr * y4.z; a3 += yr * y4.w;
        }
        nbCur = nbNext;
    }

    __syncthreads();   // protect tail yls write vs last M-phase reads

    // tail: t = 200 belongs to last chunk: y(200) = P + V(200)
    if (h == NCH - 1) {
        float Vt = nabla_V[((size_t)T_STEPS * BB + b) * DD + r];
        float yr = P + Vt;
        if (q == 0) yls[r] = yr;
        Yacc += yr;
        __syncthreads();
        float4 y4 = *(const float4*)&yls[4 * q];
        a0 += yr * y4.x; a1 += yr * y4.y; a2 += yr * y4.z; a3 += yr * y4.w;
        __syncthreads();
    }

    // chunk epilogue: m = <A, M>, write CT / Y / m
    {
        float4 A4 = *(const float4*)(ws + WS_A + r * 32 + 4 * q);
        float mp = a0 * A4.x + a1 * A4.y + a2 * A4.z + a3 * A4.w;
        red[tid] = mp;
        __syncthreads();
        for (int st = 128; st > 0; st >>= 1) {
            if (tid < st) red[tid] += red[tid + st];
            __syncthreads();
        }
        if (q == 0) {
            ws[WS_CT + (b * NCH + h) * 32 + r] = P;
            ws[WS_Y  + (b * NCH + h) * 32 + r] = Yacc;
        }
        if (tid == 0) ws[WS_M + b * NCH + h] = red[0];
    }
}

// ---------------------------------------------------------------------------
// Kernel 3 (combine): per b, resolve cross-chunk prefix algebra:
//   S = g + sum_h CT_h ; C_h = prefix ; S'_h = S - C_h
//   loss_b = w_b * sum_h [ n_h S'^T A S' - 2 S'^T A Y_h + m_h ]
// ---------------------------------------------------------------------------
__global__ __launch_bounds__(256) void combine_kernel(
    const float* __restrict__ nabla_g,
    float* __restrict__ ws)
{
    __shared__ float ct[NCH][32], Yl[NCH][32];
    __shared__ float Sv[32], Cp[32];
    __shared__ __align__(16) float sp[32];
    __shared__ float red[32];

    const int b   = blockIdx.x;
    const int tid = threadIdx.x;
    const int r   = tid >> 3;
    const int q   = tid & 7;

    if (tid < NCH * 32) {
        int hh = tid >> 5, i = tid & 31;
        ct[hh][i] = ws[WS_CT + (b * NCH + hh) * 32 + i];
        Yl[hh][i] = ws[WS_Y  + (b * NCH + hh) * 32 + i];
    }
    if (tid < 32) Cp[tid] = 0.0f;
    __syncthreads();
    if (tid < 32) {
        float s = nabla_g[b * 32 + tid];
        #pragma unroll
        for (int hh = 0; hh < NCH; ++hh) s += ct[hh][tid];
        Sv[tid] = s;
    }

    float acc = 0.0f;
    float4 A4 = *(const float4*)(ws + WS_A + r * 32 + 4 * q);
    for (int hh = 0; hh < NCH; ++hh) {
        __syncthreads();
        if (tid < 32) sp[tid] = Sv[tid] - Cp[tid];
        __syncthreads();
        float4 s4 = *(const float4*)&sp[4 * q];
        float as = A4.x * s4.x + A4.y * s4.y + A4.z * s4.z + A4.w * s4.w;
        as += __shfl_xor(as, 1);
        as += __shfl_xor(as, 2);
        as += __shfl_xor(as, 4);
        float nh = (hh == NCH - 1) ? (float)(CHT + 1) : (float)CHT;
        if (q == 0) acc += as * (nh * sp[r] - 2.0f * Yl[hh][r]);
        if (tid < 32) Cp[tid] += ct[hh][tid];
    }
    __syncthreads();
    if (q == 0) red[r] = acc;
    __syncthreads();
    if (tid == 0) {
        float s = 0.0f;
        #pragma unroll
        for (int i = 0; i < 32; ++i) s += red[i];
        #pragma unroll
        for (int hh = 0; hh < NCH; ++hh) s += ws[WS_M + b * NCH + hh];
        ws[WS_PART + b] = ws[WS_W + b] * s;
    }
}

// ---------------------------------------------------------------------------
// Kernel 4: deterministic final reduction
// ---------------------------------------------------------------------------
__global__ __launch_bounds__(512) void reduce_kernel(
    const float* __restrict__ ws, float* __restrict__ out)
{
    __shared__ float r[512];
    const int tid = threadIdx.x;
    r[tid] = ws[WS_PART + tid];
    __syncthreads();
    for (int st = 256; st > 0; st >>= 1) {
        if (tid < st) r[tid] += r[tid + st];
        __syncthreads();
    }
    if (tid == 0) out[0] = r[0] * (1.0f / (201.0f * 512.0f));
}

extern "C" void kernel_launch(void* const* d_in, const int* in_sizes, int n_in,
                              void* d_out, int out_size, void* d_ws, size_t ws_size,
                              hipStream_t stream) {
    (void)in_sizes; (void)n_in; (void)out_size; (void)ws_size;
    const float* ts       = (const float*)d_in[0];
    const float* noises   = (const float*)d_in[2];
    const float* controls = (const float*)d_in[3];
    const float* nabla_V  = (const float*)d_in[4];
    const float* nabla_f  = (const float*)d_in[5];
    const float* nabla_b  = (const float*)d_in[6];
    const float* nabla_g  = (const float*)d_in[7];
    const float* sigma    = (const float*)d_in[8];
    const float* lpd      = (const float*)d_in[9];
    const float* lps      = (const float*)d_in[10];
    const float* ltw      = (const float*)d_in[11];
    float* ws  = (float*)d_ws;
    float* out = (float*)d_out;

    prep_kernel<<<1, 512, 0, stream>>>(sigma, lpd, lps, ltw, ws);
    stream_kernel<<<dim3(NCH, BB), 256, 0, stream>>>(ts, noises, controls,
                                                     nabla_f, nabla_V, nabla_b, ws);
    combine_kernel<<<BB, 256, 0, stream>>>(nabla_g, ws);
    reduce_kernel<<<1, 512, 0, stream>>>(ws, out);
}